// Round 1
// baseline (89.278 us; speedup 1.0000x reference)
//
#include <hip/hip_runtime.h>

#define OUT_CH 128
#define TOK_PER_THREAD 32

// Kernel 1: per-edge 4-bin token histogram, packed 4x16-bit into u64.
// tokens in {0,1,2,3}; segment_ids sorted ascending.
__global__ void edge_hist_kernel(const int* __restrict__ tokens,
                                 const int* __restrict__ segids,
                                 unsigned long long* __restrict__ hist,
                                 int total_tokens) {
    int tid = blockIdx.x * blockDim.x + threadIdx.x;
    long base = (long)tid * TOK_PER_THREAD;
    if (base >= total_tokens) return;

    int cur = -1;
    unsigned long long acc = 0;

    if (base + TOK_PER_THREAD <= total_tokens) {
        const int4* tok4 = (const int4*)(tokens + base);
        const int4* seg4 = (const int4*)(segids + base);
#pragma unroll
        for (int i = 0; i < TOK_PER_THREAD / 4; ++i) {
            int4 t = tok4[i];
            int4 s = seg4[i];
            int tt[4] = {t.x, t.y, t.z, t.w};
            int ss[4] = {s.x, s.y, s.z, s.w};
#pragma unroll
            for (int j = 0; j < 4; ++j) {
                if (ss[j] != cur) {
                    if (acc) atomicAdd(&hist[cur], acc);
                    cur = ss[j];
                    acc = 0;
                }
                acc += 1ull << (tt[j] << 4);
            }
        }
    } else {
        // tail (not hit for T=2097152, kept for safety)
        for (long k = base; k < total_tokens; ++k) {
            int s = segids[k];
            int t = tokens[k];
            if (s != cur) {
                if (acc) atomicAdd(&hist[cur], acc);
                cur = s;
                acc = 0;
            }
            acc += 1ull << (t << 4);
        }
    }
    if (acc) atomicAdd(&hist[cur], acc);
}

// Kernel 2: out[e][c] = (sum_t count[e][t] * emb[t][c]) / max(total, 1)
// One thread per float4 (4 channels); 32 threads per edge.
__global__ void edge_out_kernel(const unsigned long long* __restrict__ hist,
                                const float* __restrict__ emb,
                                float* __restrict__ out,
                                int n_edges) {
    int tid = blockIdx.x * blockDim.x + threadIdx.x;
    int e = tid >> 5;          // 128/4 = 32 float4 per edge
    int c = (tid & 31) << 2;   // channel base
    if (e >= n_edges) return;

    unsigned long long h = hist[e];
    float c0 = (float)(h & 0xFFFFull);
    float c1 = (float)((h >> 16) & 0xFFFFull);
    float c2 = (float)((h >> 32) & 0xFFFFull);
    float c3 = (float)((h >> 48) & 0xFFFFull);
    float tot = c0 + c1 + c2 + c3;
    float inv = 1.0f / fmaxf(tot, 1.0f);

    const float4 e0 = *(const float4*)(emb + 0 * OUT_CH + c);
    const float4 e1 = *(const float4*)(emb + 1 * OUT_CH + c);
    const float4 e2 = *(const float4*)(emb + 2 * OUT_CH + c);
    const float4 e3 = *(const float4*)(emb + 3 * OUT_CH + c);

    float4 r;
    r.x = (c0 * e0.x + c1 * e1.x + c2 * e2.x + c3 * e3.x) * inv;
    r.y = (c0 * e0.y + c1 * e1.y + c2 * e2.y + c3 * e3.y) * inv;
    r.z = (c0 * e0.z + c1 * e1.z + c2 * e2.z + c3 * e3.z) * inv;
    r.w = (c0 * e0.w + c1 * e1.w + c2 * e2.w + c3 * e3.w) * inv;

    *(float4*)(out + (long)e * OUT_CH + c) = r;
}

extern "C" void kernel_launch(void* const* d_in, const int* in_sizes, int n_in,
                              void* d_out, int out_size, void* d_ws, size_t ws_size,
                              hipStream_t stream) {
    // inputs (setup_inputs order):
    // 0: overlap_similarity f32 [E]   (unused)
    // 1: overlap_length     f32 [E]   (unused)
    // 2: tokens             i32 [T]
    // 3: segment_ids        i32 [T]   (sorted)
    // 4: embedding          f32 [4,128]
    // 5: n_edges            i32 [1]   (device scalar; use out_size instead)
    const int* tokens = (const int*)d_in[2];
    const int* segids = (const int*)d_in[3];
    const float* emb  = (const float*)d_in[4];
    float* out = (float*)d_out;

    const int T = in_sizes[2];
    const int n_edges = out_size / OUT_CH;

    unsigned long long* hist = (unsigned long long*)d_ws;

    // zero the packed histograms (d_ws is poisoned 0xAA before every call)
    hipMemsetAsync(hist, 0, (size_t)n_edges * sizeof(unsigned long long), stream);

    int threads1 = (T + TOK_PER_THREAD - 1) / TOK_PER_THREAD;
    int blocks1 = (threads1 + 255) / 256;
    edge_hist_kernel<<<blocks1, 256, 0, stream>>>(tokens, segids, hist, T);

    int threads2 = n_edges * (OUT_CH / 4);
    int blocks2 = (threads2 + 255) / 256;
    edge_out_kernel<<<blocks2, 256, 0, stream>>>(hist, emb, out, n_edges);
}